// Round 2
// baseline (804.869 us; speedup 1.0000x reference)
//
#include <hip/hip_runtime.h>
#include <stdint.h>

typedef unsigned short u16;
typedef __attribute__((ext_vector_type(8))) __bf16 bf16x8;
typedef __attribute__((ext_vector_type(8))) u16 u16x8;
typedef __attribute__((ext_vector_type(4))) float f32x4;

#define HID 2048
#define INTER 5632
#define TOKENS 8192

// fp32 -> bf16 round-to-nearest-even (inputs are normal floats, no NaN path needed)
__device__ __forceinline__ u16 f2bf(float f) {
  uint32_t u = __builtin_bit_cast(uint32_t, f);
  u += 0x7fffu + ((u >> 16) & 1u);
  return (u16)(u >> 16);
}

// async global->LDS, 16B per lane. LDS dest must be wave-uniform-base + lane*16.
__device__ __forceinline__ void gld_lds16(const u16* g, u16* l) {
  __builtin_amdgcn_global_load_lds(
      (const __attribute__((address_space(1))) unsigned int*)g,
      (__attribute__((address_space(3))) unsigned int*)l, 16, 0, 0);
}

// ---------------- conversion kernels ----------------

__global__ void k_cvt_x(const float* __restrict__ in, u16* __restrict__ out) {
  size_t i = (size_t)blockIdx.x * 256 + threadIdx.x; // 8 elems/thread
  const float4* p = (const float4*)(in + i * 8);
  float4 a = p[0], b = p[1];
  u16x8 o;
  o[0] = f2bf(a.x); o[1] = f2bf(a.y); o[2] = f2bf(a.z); o[3] = f2bf(a.w);
  o[4] = f2bf(b.x); o[5] = f2bf(b.y); o[6] = f2bf(b.z); o[7] = f2bf(b.w);
  *(u16x8*)(out + i * 8) = o;
}

// in: [R][C] f32  ->  out: [C][R] bf16
__global__ void k_transpose(const float* __restrict__ in, u16* __restrict__ out,
                            int R, int C) {
  __shared__ float t[32][33];
  int c0 = blockIdx.x * 32, r0 = blockIdx.y * 32;
  int tx = threadIdx.x, ty = threadIdx.y;
#pragma unroll
  for (int r = 0; r < 4; ++r) {
    int i = ty + r * 8;
    t[i][tx] = in[(size_t)(r0 + i) * C + c0 + tx];
  }
  __syncthreads();
#pragma unroll
  for (int r = 0; r < 4; ++r) {
    int i = ty + r * 8;
    out[(size_t)(c0 + i) * R + r0 + tx] = f2bf(t[tx][i]);
  }
}

// ---------------- GEMM1: gate_up + SwiGLU fused ----------------
// A = x_bf16 [8192][2048]; B rows from W1^T [11264][2048]:
//   gate rows at n, up rows at n+INTER.
// Block: 128 M-rows x 64 INTER-cols (both gate and up) -> hidden bf16.
__global__ __launch_bounds__(256, 2) void k_gemm1(
    const u16* __restrict__ xb, const u16* __restrict__ w1t,
    u16* __restrict__ hid) {
  __shared__ __align__(16) u16 sA[128 * 64];
  __shared__ __align__(16) u16 sG[64 * 64];
  __shared__ __align__(16) u16 sU[64 * 64];
  const int K = HID;
  int brow = blockIdx.y * 128, bcol = blockIdx.x * 64;
  int tid = threadIdx.x, lane = tid & 63, wid = tid >> 6;
  int wm = wid >> 1, wn = wid & 1;
  f32x4 accg[4][2] = {}, accu[4][2] = {};
  const u16* gA = xb + (size_t)brow * K;
  const u16* gG = w1t + (size_t)bcol * K;
  const u16* gU = w1t + (size_t)(bcol + INTER) * K;
  int tr = tid >> 3;           // 0..31 (row within 32-row staging stripe)
  int tc = (tid & 7) * 8;      // k element offset, 8 bf16 = 16B per lane
  int cb = lane & 15, kb = (lane >> 4) * 8;

  for (int kt = 0; kt < K / 64; ++kt) {
    int k0 = kt * 64;
#pragma unroll
    for (int r = 0; r < 4; ++r) {
      int row = r * 32 + tr;
      gld_lds16(gA + (size_t)row * K + k0 + tc, &sA[row * 64 + tc]);
    }
#pragma unroll
    for (int r = 0; r < 2; ++r) {
      int row = r * 32 + tr;
      gld_lds16(gG + (size_t)row * K + k0 + tc, &sG[row * 64 + tc]);
      gld_lds16(gU + (size_t)row * K + k0 + tc, &sU[row * 64 + tc]);
    }
    __syncthreads();
#pragma unroll
    for (int ks = 0; ks < 2; ++ks) {
      int kk = ks * 32 + kb;
      bf16x8 af[4];
#pragma unroll
      for (int m = 0; m < 4; ++m)
        af[m] = *(const bf16x8*)&sA[(wm * 64 + m * 16 + cb) * 64 + kk];
#pragma unroll
      for (int n = 0; n < 2; ++n) {
        bf16x8 bg = *(const bf16x8*)&sG[(wn * 32 + n * 16 + cb) * 64 + kk];
        bf16x8 bu = *(const bf16x8*)&sU[(wn * 32 + n * 16 + cb) * 64 + kk];
#pragma unroll
        for (int m = 0; m < 4; ++m) {
          accg[m][n] = __builtin_amdgcn_mfma_f32_16x16x32_bf16(af[m], bg, accg[m][n], 0, 0, 0);
          accu[m][n] = __builtin_amdgcn_mfma_f32_16x16x32_bf16(af[m], bu, accu[m][n], 0, 0, 0);
        }
      }
    }
    __syncthreads();
  }
  int rb = (lane >> 4) * 4;
#pragma unroll
  for (int m = 0; m < 4; ++m)
#pragma unroll
    for (int n = 0; n < 2; ++n) {
      int col = bcol + wn * 32 + n * 16 + cb;
#pragma unroll
      for (int i = 0; i < 4; ++i) {
        int row = brow + wm * 64 + m * 16 + rb + i;
        float g = accg[m][n][i], u = accu[m][n][i];
        float h = g / (1.0f + __expf(-g)) * u;
        hid[(size_t)row * INTER + col] = f2bf(h);
      }
    }
}

// ---------------- GEMM2: out = hidden @ W2 ----------------
// A = hidden bf16 [8192][5632]; B = W2^T bf16 [2048][5632]; C fp32 [8192][2048].
__global__ __launch_bounds__(256, 2) void k_gemm2(
    const u16* __restrict__ hid, const u16* __restrict__ w2t,
    float* __restrict__ out) {
  __shared__ __align__(16) u16 sA[128 * 64];
  __shared__ __align__(16) u16 sB[128 * 64];
  const int K = INTER;
  int brow = blockIdx.y * 128, bcol = blockIdx.x * 128;
  int tid = threadIdx.x, lane = tid & 63, wid = tid >> 6;
  int wm = wid >> 1, wn = wid & 1;
  f32x4 acc[4][4] = {};
  const u16* gA = hid + (size_t)brow * K;
  const u16* gB = w2t + (size_t)bcol * K;
  int tr = tid >> 3, tc = (tid & 7) * 8;
  int cb = lane & 15, kb = (lane >> 4) * 8;

  for (int kt = 0; kt < K / 64; ++kt) {
    int k0 = kt * 64;
#pragma unroll
    for (int r = 0; r < 4; ++r) {
      int row = r * 32 + tr;
      gld_lds16(gA + (size_t)row * K + k0 + tc, &sA[row * 64 + tc]);
      gld_lds16(gB + (size_t)row * K + k0 + tc, &sB[row * 64 + tc]);
    }
    __syncthreads();
#pragma unroll
    for (int ks = 0; ks < 2; ++ks) {
      int kk = ks * 32 + kb;
      bf16x8 af[4], bq[4];
#pragma unroll
      for (int m = 0; m < 4; ++m)
        af[m] = *(const bf16x8*)&sA[(wm * 64 + m * 16 + cb) * 64 + kk];
#pragma unroll
      for (int n = 0; n < 4; ++n)
        bq[n] = *(const bf16x8*)&sB[(wn * 64 + n * 16 + cb) * 64 + kk];
#pragma unroll
      for (int n = 0; n < 4; ++n)
#pragma unroll
        for (int m = 0; m < 4; ++m)
          acc[m][n] = __builtin_amdgcn_mfma_f32_16x16x32_bf16(af[m], bq[n], acc[m][n], 0, 0, 0);
    }
    __syncthreads();
  }
  int rb = (lane >> 4) * 4;
#pragma unroll
  for (int m = 0; m < 4; ++m)
#pragma unroll
    for (int n = 0; n < 4; ++n) {
      int col = bcol + wn * 64 + n * 16 + cb;
#pragma unroll
      for (int i = 0; i < 4; ++i) {
        int row = brow + wm * 64 + m * 16 + rb + i;
        out[(size_t)row * HID + col] = acc[m][n][i];
      }
    }
}

// ---------------- launch ----------------

extern "C" void kernel_launch(void* const* d_in, const int* in_sizes, int n_in,
                              void* d_out, int out_size, void* d_ws, size_t ws_size,
                              hipStream_t stream) {
  const float* x  = (const float*)d_in[0];   // [8192][2048]
  const float* w1 = (const float*)d_in[1];   // [2048][11264]
  const float* w2 = (const float*)d_in[2];   // [5632][2048]
  float* out = (float*)d_out;

  // workspace layout (bytes)
  const size_t off_xb  = 0;                         // 8192*2048*2   = 33554432
  const size_t off_w1t = 33554432;                  // 11264*2048*2  = 46137344
  const size_t off_w2t = off_w1t + 46137344;        // 2048*5632*2   = 23068672
  const size_t off_hid = off_w2t + 23068672;        // 8192*5632*2   = 92274688
  const size_t need    = off_hid + 92274688;        // ~195 MB
  if (ws_size < need) return;  // loud failure (absmax) rather than OOB writes

  char* ws = (char*)d_ws;
  u16* xb  = (u16*)(ws + off_xb);
  u16* w1t = (u16*)(ws + off_w1t);
  u16* w2t = (u16*)(ws + off_w2t);
  u16* hid = (u16*)(ws + off_hid);

  k_cvt_x<<<TOKENS * HID / 8 / 256, 256, 0, stream>>>(x, xb);
  dim3 tb(32, 8);
  k_transpose<<<dim3((2 * INTER) / 32, HID / 32), tb, 0, stream>>>(w1, w1t, HID, 2 * INTER);
  k_transpose<<<dim3(HID / 32, INTER / 32), tb, 0, stream>>>(w2, w2t, INTER, HID);

  k_gemm1<<<dim3(INTER / 64, TOKENS / 128), 256, 0, stream>>>(xb, w1t, hid);
  k_gemm2<<<dim3(HID / 128, TOKENS / 128), 256, 0, stream>>>(hid, w2t, out);
}